// Round 1
// baseline (18374.780 us; speedup 1.0000x reference)
//
#include <hip/hip_runtime.h>
#include <hip/hip_cooperative_groups.h>

namespace cg = cooperative_groups;

typedef unsigned short u16;
typedef short bf16x8 __attribute__((ext_vector_type(8)));
typedef float f32x4 __attribute__((ext_vector_type(4)));

#define NB 128
#define NT 512
#define NV 1024
#define NE 256
#define NH 512
#define NG 2048

__device__ __forceinline__ u16 f2bf(float f) {
  union { float f; unsigned u; } v; v.f = f;
  unsigned r = v.u + 0x7FFFu + ((v.u >> 16) & 1u);
  return (u16)(r >> 16);
}
__device__ __forceinline__ float bf2f(u16 u) {
  union { unsigned u; float f; } v; v.u = ((unsigned)u) << 16;
  return v.f;
}
__device__ __forceinline__ float sigm(float x) { return 1.f / (1.f + __expf(-x)); }
__device__ __forceinline__ float tanh_f(float x) {
  x = fminf(fmaxf(x, -20.f), 20.f);
  float e = __expf(2.f * x);
  return (e - 1.f) / (e + 1.f);
}

#define MFMA16(a, b, c) __builtin_amdgcn_mfma_f32_16x16x32_bf16((a), (b), (c), 0, 0, 0)

// ---------------------------------------------------------------------------
// Kernel 1: weight prep. Gate rows permuted: r' = j*4 + gate  (orig = gate*NH + j)
// so the recurrence MFMA puts i,f,g,o of one j into one lane's 4 acc regs.
// Also writes h0 (mean over layer dim) as bf16 into hs slot 0.
// ---------------------------------------------------------------------------
__global__ __launch_bounds__(256) void prep_kernel(
    const float* __restrict__ enc_h, const float* __restrict__ W_ih,
    const float* __restrict__ W_hh, const float* __restrict__ b_ih,
    const float* __restrict__ b_hh, const float* __restrict__ W_out,
    u16* __restrict__ wih_p, u16* __restrict__ whh_p, u16* __restrict__ wout_b,
    float* __restrict__ bias_p, u16* __restrict__ hs0) {
  int idx = blockIdx.x * 256 + threadIdx.x;
  int stride = gridDim.x * 256;
  const int N0 = NG * NE, N1 = NG * NH, N2 = NV * NH, N3 = NG, N4 = NB * NH;
  int total = N0 + N1 + N2 + N3 + N4;
  for (int i = idx; i < total; i += stride) {
    int j = i;
    if (j < N0) {
      int r = j >> 8, k = j & 255;
      int orig = (r & 3) * NH + (r >> 2);
      wih_p[j] = f2bf(W_ih[orig * NE + k]);
    } else if ((j -= N0) < N1) {
      int r = j >> 9, k = j & 511;
      int orig = (r & 3) * NH + (r >> 2);
      whh_p[j] = f2bf(W_hh[orig * NH + k]);
    } else if ((j -= N1) < N2) {
      wout_b[j] = f2bf(W_out[j]);
    } else if ((j -= N2) < N3) {
      int orig = (j & 3) * NH + (j >> 2);
      bias_p[j] = b_ih[orig] + b_hh[orig];
    } else {
      j -= N3;
      hs0[j] = f2bf(0.5f * (enc_h[j] + enc_h[N4 + j]));
    }
  }
}

// ---------------------------------------------------------------------------
// Kernel 2: gates_x = relu(emb[tok]) @ W_ih_p^T + bias_p   -> bf16 (t,b,g')
// Tile: one t (128 batch rows) x 128 gate cols per WG. A staged in LDS
// (XOR-swizzled, G4), B read direct from L2-resident permuted weights.
// Output written into d_out (aliased as bf16 scratch).
// ---------------------------------------------------------------------------
__global__ __launch_bounds__(256) void gates_kernel(
    const int* __restrict__ target, const float* __restrict__ emb,
    const u16* __restrict__ wih_p, const float* __restrict__ bias_p,
    u16* __restrict__ gates) {
  __shared__ __align__(16) u16 As[NB * NE];  // 64 KB, 16B-granule xor swizzle
  int t = blockIdx.y, nTile = blockIdx.x, tid = threadIdx.x;
  for (int i = tid; i < NB * 64; i += 256) {
    int row = i >> 6, c = i & 63;
    int tok = (t == 0) ? 0 : target[row * NT + t - 1];
    float4 f = *(const float4*)(emb + (size_t)tok * NE + c * 4);
    ushort4 pk = make_ushort4(f2bf(fmaxf(f.x, 0.f)), f2bf(fmaxf(f.y, 0.f)),
                              f2bf(fmaxf(f.z, 0.f)), f2bf(fmaxf(f.w, 0.f)));
    int g = c >> 1;
    int off = row * NE + ((((g ^ (row & 7)) << 3)) | ((c & 1) << 2));
    *(ushort4*)&As[off] = pk;
  }
  __syncthreads();
  int w = tid >> 6, lane = tid & 63, l15 = lane & 15, l4 = lane >> 4;
  int mOff = (w & 1) * 64, nOff = (w >> 1) * 64;
  f32x4 acc[4][4] = {};
  for (int kk = 0; kk < 8; ++kk) {
    bf16x8 a[4], bb[4];
    for (int fm = 0; fm < 4; ++fm) {
      int row = mOff + fm * 16 + l15;
      a[fm] = *(const bf16x8*)&As[row * NE + (((kk * 4 + l4) ^ (row & 7)) << 3)];
    }
    int k0 = kk * 32 + l4 * 8;
    for (int fn = 0; fn < 4; ++fn) {
      int n = nTile * 128 + nOff + fn * 16 + l15;
      bb[fn] = *(const bf16x8*)(wih_p + (size_t)n * NE + k0);
    }
    for (int fm = 0; fm < 4; ++fm)
      for (int fn = 0; fn < 4; ++fn)
        acc[fm][fn] = MFMA16(a[fm], bb[fn], acc[fm][fn]);
  }
  for (int fn = 0; fn < 4; ++fn) {
    int n = nTile * 128 + nOff + fn * 16 + l15;
    float bias = bias_p[n];
    for (int fm = 0; fm < 4; ++fm)
      for (int i2 = 0; i2 < 4; ++i2) {
        int row = mOff + fm * 16 + l4 * 4 + i2;
        gates[((size_t)t * NB + row) * NG + n] = f2bf(acc[fm][fn][i2] + bias);
      }
  }
}

// ---------------------------------------------------------------------------
// Kernel 3: persistent cooperative LSTM scan. 128 WGs = 4 batch-slices(32) x
// 32 j-slices(16). Each WG holds its 64 permuted W_hh rows in LDS (64 KB,
// xor-swizzled) and its c-state in registers across all T steps.
// MFMA computes D(gate x batch) = W_slice . h^T so each lane owns i,f,g,o of
// one (j,b): the pointwise update is lane-local. hs is the (T+1)-deep h chain
// (slot 0 = h0); one grid sync per step.
// ---------------------------------------------------------------------------
__global__ __launch_bounds__(256) void lstm_kernel(
    const float* __restrict__ enc_c, const u16* __restrict__ gates,
    const u16* __restrict__ whh_p, u16* __restrict__ hs,
    float* __restrict__ out_tail) {
  cg::grid_group grid = cg::this_grid();
  __shared__ __align__(16) u16 Wsm[64 * NH];  // 64 KB
  int bid = blockIdx.x;
  int gb = bid & 3, gj = bid >> 2;
  int tid = threadIdx.x;
  for (int i = tid; i < 64 * 64; i += 256) {
    int row = i >> 6, c = i & 63;
    *(uint4*)&Wsm[row * NH + ((c ^ (row & 7)) << 3)] =
        *(const uint4*)(whh_p + (size_t)(gj * 64 + row) * NH + c * 8);
  }
  int w = tid >> 6, lane = tid & 63, l15 = lane & 15, l4 = lane >> 4;
  int jm = gj * 16 + w * 4 + l4;  // this lane's j index
  int b0 = gb * 32 + l15;         // batch (n=0); n=1 -> +16
  float creg[2];
  creg[0] = 0.5f * (enc_c[b0 * NH + jm] + enc_c[NB * NH + b0 * NH + jm]);
  creg[1] = 0.5f * (enc_c[(b0 + 16) * NH + jm] + enc_c[NB * NH + (b0 + 16) * NH + jm]);
  __syncthreads();
  int arow = w * 16 + l15;
  int sw = arow & 7;
  for (int t = 0; t < NT; ++t) {
    f32x4 acc[2];
    const u16* hsrc = hs + (size_t)t * (NB * NH);
    for (int n = 0; n < 2; ++n) {
      const u16* gp = gates + ((size_t)t * NB + b0 + n * 16) * NG + jm * 4;
      ushort4 gv = *(const ushort4*)gp;
      acc[n][0] = bf2f(gv.x); acc[n][1] = bf2f(gv.y);
      acc[n][2] = bf2f(gv.z); acc[n][3] = bf2f(gv.w);
    }
#pragma unroll
    for (int kk = 0; kk < 16; ++kk) {
      bf16x8 a = *(const bf16x8*)&Wsm[arow * NH + (((kk * 4 + l4) ^ sw) << 3)];
      int k0 = kk * 32 + l4 * 8;
      bf16x8 h0v = *(const bf16x8*)(hsrc + (size_t)b0 * NH + k0);
      bf16x8 h1v = *(const bf16x8*)(hsrc + (size_t)(b0 + 16) * NH + k0);
      acc[0] = MFMA16(a, h0v, acc[0]);
      acc[1] = MFMA16(a, h1v, acc[1]);
    }
    u16* hdst = hs + (size_t)(t + 1) * (NB * NH);
    for (int n = 0; n < 2; ++n) {
      float ig = sigm(acc[n][0]);
      float fg = sigm(acc[n][1]);
      float gg = tanh_f(acc[n][2]);
      float og = sigm(acc[n][3]);
      float cn = fg * creg[n] + ig * gg;
      creg[n] = cn;
      float hn = og * tanh_f(cn);
      hdst[(b0 + n * 16) * NH + jm] = f2bf(hn);
      if (t == NT - 1) {
        out_tail[(b0 + n * 16) * NH + jm] = hn;             // h_T
        out_tail[NB * NH + (b0 + n * 16) * NH + jm] = cn;   // c_T
      }
    }
    if (t < NT - 1) {
      __threadfence();  // release h writes to device scope before barrier
      grid.sync();
    }
  }
}

// ---------------------------------------------------------------------------
// Kernel 4: logits = hs[1..T] @ W_out^T + b_out  -> fp32 into d_out rows (b*T+t)
// ---------------------------------------------------------------------------
__global__ __launch_bounds__(256) void logits_kernel(
    const u16* __restrict__ hs, const u16* __restrict__ wout_b,
    const float* __restrict__ b_out, float* __restrict__ out) {
  int mTile = blockIdx.y, nTile = blockIdx.x;
  int tid = threadIdx.x, w = tid >> 6, lane = tid & 63, l15 = lane & 15, l4 = lane >> 4;
  int mOff = (w & 1) * 64, nOff = (w >> 1) * 64;
  const u16* A = hs + (size_t)NB * NH;  // skip h0; row m = t*NB + b
  f32x4 acc[4][4] = {};
  for (int kk = 0; kk < 16; ++kk) {
    int k0 = kk * 32 + l4 * 8;
    bf16x8 a[4], bb[4];
    for (int fm = 0; fm < 4; ++fm) {
      int m = mTile * 128 + mOff + fm * 16 + l15;
      a[fm] = *(const bf16x8*)(A + (size_t)m * NH + k0);
    }
    for (int fn = 0; fn < 4; ++fn) {
      int v = nTile * 128 + nOff + fn * 16 + l15;
      bb[fn] = *(const bf16x8*)(wout_b + (size_t)v * NH + k0);
    }
    for (int fm = 0; fm < 4; ++fm)
      for (int fn = 0; fn < 4; ++fn)
        acc[fm][fn] = MFMA16(a[fm], bb[fn], acc[fm][fn]);
  }
  for (int fn = 0; fn < 4; ++fn) {
    int v = nTile * 128 + nOff + fn * 16 + l15;
    float bias = b_out[v];
    for (int fm = 0; fm < 4; ++fm)
      for (int i2 = 0; i2 < 4; ++i2) {
        int m = mTile * 128 + mOff + fm * 16 + l4 * 4 + i2;
        int b = m & (NB - 1), tt = m >> 7;
        out[((size_t)b * NT + tt) * NV + v] = acc[fm][fn][i2] + bias;
      }
  }
}

// ---------------------------------------------------------------------------
// Kernel 5: in-place row log_softmax over V=1024. One wave per row.
// ---------------------------------------------------------------------------
__global__ __launch_bounds__(256) void lsm_kernel(float* __restrict__ out) {
  int row = blockIdx.x * 4 + (threadIdx.x >> 6);
  int lane = threadIdx.x & 63;
  float* p = out + (size_t)row * NV + lane * 4;
  float4 x[4];
  float m = -1e30f;
#pragma unroll
  for (int i = 0; i < 4; ++i) {
    x[i] = *(const float4*)(p + i * 256);
    m = fmaxf(m, fmaxf(fmaxf(x[i].x, x[i].y), fmaxf(x[i].z, x[i].w)));
  }
#pragma unroll
  for (int o = 1; o < 64; o <<= 1) m = fmaxf(m, __shfl_xor(m, o, 64));
  float s = 0.f;
#pragma unroll
  for (int i = 0; i < 4; ++i)
    s += __expf(x[i].x - m) + __expf(x[i].y - m) + __expf(x[i].z - m) + __expf(x[i].w - m);
#pragma unroll
  for (int o = 1; o < 64; o <<= 1) s += __shfl_xor(s, o, 64);
  float lse = m + __logf(s);
#pragma unroll
  for (int i = 0; i < 4; ++i) {
    float4 y = x[i];
    y.x -= lse; y.y -= lse; y.z -= lse; y.w -= lse;
    *(float4*)(p + i * 256) = y;
  }
}

extern "C" void kernel_launch(void* const* d_in, const int* in_sizes, int n_in,
                              void* d_out, int out_size, void* d_ws, size_t ws_size,
                              hipStream_t stream) {
  (void)in_sizes; (void)n_in; (void)out_size; (void)ws_size;
  // inputs (setup_inputs order); d_in[0] = encoder_outputs is unused by the math
  const float* enc_h  = (const float*)d_in[1];
  const float* enc_c  = (const float*)d_in[2];
  const int*   target = (const int*)d_in[3];
  const float* emb    = (const float*)d_in[4];
  const float* W_ih   = (const float*)d_in[5];
  const float* W_hh   = (const float*)d_in[6];
  const float* b_ih   = (const float*)d_in[7];
  const float* b_hh   = (const float*)d_in[8];
  const float* W_out  = (const float*)d_in[9];
  const float* b_out  = (const float*)d_in[10];

  char* ws = (char*)d_ws;
  u16*   wih_p  = (u16*)(ws);                 // 2048x256 bf16   (1 MB)
  u16*   whh_p  = (u16*)(ws + 1048576);       // 2048x512 bf16   (2 MB)
  u16*   wout_b = (u16*)(ws + 3145728);       // 1024x512 bf16   (1 MB)
  float* bias_p = (float*)(ws + 4194304);     // 2048 f32
  u16*   hs     = (u16*)(ws + 4202496);       // (T+1)x128x512 bf16 (64.1 MB)

  u16*   gates  = (u16*)d_out;                       // 268 MB bf16, aliases log_probs
  float* out    = (float*)d_out;
  float* out_tail = out + (size_t)NB * NT * NV;      // h_T then c_T

  prep_kernel<<<dim3(2048), 256, 0, stream>>>(enc_h, W_ih, W_hh, b_ih, b_hh, W_out,
                                              wih_p, whh_p, wout_b, bias_p, hs);
  gates_kernel<<<dim3(16, 512), 256, 0, stream>>>(target, emb, wih_p, bias_p, gates);
  {
    const float* enc_c_a = enc_c;
    const u16* gates_a = gates;
    const u16* whh_a = whh_p;
    u16* hs_a = hs;
    float* tail_a = out_tail;
    void* args[] = {&enc_c_a, &gates_a, &whh_a, &hs_a, &tail_a};
    hipLaunchCooperativeKernel((const void*)lstm_kernel, dim3(128), dim3(256),
                               args, 0, stream);
  }
  logits_kernel<<<dim3(8, 512), 256, 0, stream>>>(hs, wout_b, b_out, out);
  lsm_kernel<<<16384, 256, 0, stream>>>(out);
}

// Round 2
// 4907.079 us; speedup vs baseline: 3.7445x; 3.7445x over previous
//
#include <hip/hip_runtime.h>

typedef unsigned short u16;
typedef short bf16x8 __attribute__((ext_vector_type(8)));
typedef float f32x4 __attribute__((ext_vector_type(4)));

#define NB 128
#define NT 512
#define NV 1024
#define NE 256
#define NH 512
#define NG 2048

__device__ __forceinline__ u16 f2bf(float f) {
  union { float f; unsigned u; } v; v.f = f;
  unsigned r = v.u + 0x7FFFu + ((v.u >> 16) & 1u);
  return (u16)(r >> 16);
}
__device__ __forceinline__ float bf2f(u16 u) {
  union { unsigned u; float f; } v; v.u = ((unsigned)u) << 16;
  return v.f;
}
__device__ __forceinline__ float sigm(float x) { return 1.f / (1.f + __expf(-x)); }
__device__ __forceinline__ float tanh_f(float x) {
  x = fminf(fmaxf(x, -20.f), 20.f);
  float e = __expf(2.f * x);
  return (e - 1.f) / (e + 1.f);
}

#define MFMA16(a, b, c) __builtin_amdgcn_mfma_f32_16x16x32_bf16((a), (b), (c), 0, 0, 0)

// device-coherent (cross-XCD, via shared L3) helpers — no cache flushes
__device__ __forceinline__ unsigned long long dc_load_u64(const void* p) {
  return __hip_atomic_load((const unsigned long long*)p, __ATOMIC_RELAXED,
                           __HIP_MEMORY_SCOPE_AGENT);
}
__device__ __forceinline__ void dc_store_u16(u16* p, u16 v) {
  __hip_atomic_store(p, v, __ATOMIC_RELAXED, __HIP_MEMORY_SCOPE_AGENT);
}

// ---------------------------------------------------------------------------
// Kernel 1: weight prep (gate rows permuted r' = j*4 + gate), h0 into hs slot
// 0, barrier counter zeroed.
// ---------------------------------------------------------------------------
__global__ __launch_bounds__(256) void prep_kernel(
    const float* __restrict__ enc_h, const float* __restrict__ W_ih,
    const float* __restrict__ W_hh, const float* __restrict__ b_ih,
    const float* __restrict__ b_hh, const float* __restrict__ W_out,
    u16* __restrict__ wih_p, u16* __restrict__ whh_p, u16* __restrict__ wout_b,
    float* __restrict__ bias_p, u16* __restrict__ hs0,
    unsigned* __restrict__ bar) {
  int idx = blockIdx.x * 256 + threadIdx.x;
  int stride = gridDim.x * 256;
  if (idx == 0) __hip_atomic_store(bar, 0u, __ATOMIC_RELAXED, __HIP_MEMORY_SCOPE_AGENT);
  const int N0 = NG * NE, N1 = NG * NH, N2 = NV * NH, N3 = NG, N4 = NB * NH;
  int total = N0 + N1 + N2 + N3 + N4;
  for (int i = idx; i < total; i += stride) {
    int j = i;
    if (j < N0) {
      int r = j >> 8, k = j & 255;
      int orig = (r & 3) * NH + (r >> 2);
      wih_p[j] = f2bf(W_ih[orig * NE + k]);
    } else if ((j -= N0) < N1) {
      int r = j >> 9, k = j & 511;
      int orig = (r & 3) * NH + (r >> 2);
      whh_p[j] = f2bf(W_hh[orig * NH + k]);
    } else if ((j -= N1) < N2) {
      wout_b[j] = f2bf(W_out[j]);
    } else if ((j -= N2) < N3) {
      int orig = (j & 3) * NH + (j >> 2);
      bias_p[j] = b_ih[orig] + b_hh[orig];
    } else {
      j -= N3;
      hs0[j] = f2bf(0.5f * (enc_h[j] + enc_h[N4 + j]));
    }
  }
}

// ---------------------------------------------------------------------------
// Kernel 2: gates_x = relu(emb[tok]) @ W_ih_p^T + bias_p   -> bf16 (t,b,g')
// ---------------------------------------------------------------------------
__global__ __launch_bounds__(256) void gates_kernel(
    const int* __restrict__ target, const float* __restrict__ emb,
    const u16* __restrict__ wih_p, const float* __restrict__ bias_p,
    u16* __restrict__ gates) {
  __shared__ __align__(16) u16 As[NB * NE];  // 64 KB, 16B-granule xor swizzle
  int t = blockIdx.y, nTile = blockIdx.x, tid = threadIdx.x;
  for (int i = tid; i < NB * 64; i += 256) {
    int row = i >> 6, c = i & 63;
    int tok = (t == 0) ? 0 : target[row * NT + t - 1];
    float4 f = *(const float4*)(emb + (size_t)tok * NE + c * 4);
    ushort4 pk = make_ushort4(f2bf(fmaxf(f.x, 0.f)), f2bf(fmaxf(f.y, 0.f)),
                              f2bf(fmaxf(f.z, 0.f)), f2bf(fmaxf(f.w, 0.f)));
    int g = c >> 1;
    int off = row * NE + ((((g ^ (row & 7)) << 3)) | ((c & 1) << 2));
    *(ushort4*)&As[off] = pk;
  }
  __syncthreads();
  int w = tid >> 6, lane = tid & 63, l15 = lane & 15, l4 = lane >> 4;
  int mOff = (w & 1) * 64, nOff = (w >> 1) * 64;
  f32x4 acc[4][4] = {};
  for (int kk = 0; kk < 8; ++kk) {
    bf16x8 a[4], bb[4];
    for (int fm = 0; fm < 4; ++fm) {
      int row = mOff + fm * 16 + l15;
      a[fm] = *(const bf16x8*)&As[row * NE + (((kk * 4 + l4) ^ (row & 7)) << 3)];
    }
    int k0 = kk * 32 + l4 * 8;
    for (int fn = 0; fn < 4; ++fn) {
      int n = nTile * 128 + nOff + fn * 16 + l15;
      bb[fn] = *(const bf16x8*)(wih_p + (size_t)n * NE + k0);
    }
    for (int fm = 0; fm < 4; ++fm)
      for (int fn = 0; fn < 4; ++fn)
        acc[fm][fn] = MFMA16(a[fm], bb[fn], acc[fm][fn]);
  }
  for (int fn = 0; fn < 4; ++fn) {
    int n = nTile * 128 + nOff + fn * 16 + l15;
    float bias = bias_p[n];
    for (int fm = 0; fm < 4; ++fm)
      for (int i2 = 0; i2 < 4; ++i2) {
        int row = mOff + fm * 16 + l4 * 4 + i2;
        gates[((size_t)t * NB + row) * NG + n] = f2bf(acc[fm][fn][i2] + bias);
      }
  }
}

// ---------------------------------------------------------------------------
// Kernel 3: persistent LSTM scan, custom L3 barrier (no L2 flushes).
// 128 WGs = 4 batch-slices(32) x 32 j-slices(16). W_hh fragments preloaded
// into 64 VGPRs/lane; per step the 32KB h-slice is staged into LDS via
// device-coherent 8B loads (XOR-swizzled), h writes are device-coherent 2B
// stores, and WG leaders rendezvous on a monotonic L3 atomic counter.
// ---------------------------------------------------------------------------
__global__ __launch_bounds__(256) void lstm_kernel(
    const float* __restrict__ enc_c, const u16* __restrict__ gates,
    const u16* __restrict__ whh_p, u16* __restrict__ hs,
    float* __restrict__ out_tail, unsigned* __restrict__ bar) {
  __shared__ __align__(16) u16 Hs[32 * NH];  // 32 KB h-slice, xor-swizzled
  int bid = blockIdx.x;
  int gb = bid & 3, gj = bid >> 2;
  int tid = threadIdx.x;
  int w = tid >> 6, lane = tid & 63, l15 = lane & 15, l4 = lane >> 4;
  int jm = gj * 16 + w * 4 + l4;  // this lane's j index
  int b0 = gb * 32 + l15;         // batch (n=0); n=1 -> +16

  // W_hh A-fragments into registers: row gj*64 + w*16 + l15, k = kk*32+l4*8
  bf16x8 wreg[16];
  {
    const u16* wp = whh_p + (size_t)(gj * 64 + w * 16 + l15) * NH + l4 * 8;
#pragma unroll
    for (int kk = 0; kk < 16; ++kk) wreg[kk] = *(const bf16x8*)(wp + kk * 32);
  }
  float creg[2];
  creg[0] = 0.5f * (enc_c[b0 * NH + jm] + enc_c[NB * NH + b0 * NH + jm]);
  creg[1] = 0.5f * (enc_c[(b0 + 16) * NH + jm] + enc_c[NB * NH + (b0 + 16) * NH + jm]);

  for (int t = 0; t < NT; ++t) {
    // stage h[t] slice (32 batches x 512) into LDS, device-coherent loads
    const u16* hsrc = hs + (size_t)t * (NB * NH) + (size_t)gb * 32 * NH;
#pragma unroll
    for (int j = 0; j < 8; ++j) {
      int ch = j * 256 + tid;            // 16B chunk id, 0..2047
      int row = ch >> 6, c = ch & 63;
      const u16* src = hsrc + row * NH + c * 8;
      unsigned long long q0 = dc_load_u64(src);
      unsigned long long q1 = dc_load_u64(src + 4);
      u16* dst = &Hs[row * NH + (((c ^ (row & 7))) << 3)];
      ((unsigned long long*)dst)[0] = q0;
      ((unsigned long long*)dst)[1] = q1;
    }
    __syncthreads();

    f32x4 acc[2];
    {
      const u16* gp = gates + ((size_t)t * NB + b0) * NG + jm * 4;
      ushort4 gv0 = *(const ushort4*)gp;
      ushort4 gv1 = *(const ushort4*)(gp + 16 * NG);
      acc[0][0] = bf2f(gv0.x); acc[0][1] = bf2f(gv0.y);
      acc[0][2] = bf2f(gv0.z); acc[0][3] = bf2f(gv0.w);
      acc[1][0] = bf2f(gv1.x); acc[1][1] = bf2f(gv1.y);
      acc[1][2] = bf2f(gv1.z); acc[1][3] = bf2f(gv1.w);
    }
#pragma unroll
    for (int kk = 0; kk < 16; ++kk) {
      int K = kk * 4 + l4;
      bf16x8 h0v = *(const bf16x8*)&Hs[l15 * NH + ((K ^ (l15 & 7)) << 3)];
      bf16x8 h1v = *(const bf16x8*)&Hs[(l15 + 16) * NH + ((K ^ (l15 & 7)) << 3)];
      acc[0] = MFMA16(wreg[kk], h0v, acc[0]);
      acc[1] = MFMA16(wreg[kk], h1v, acc[1]);
    }
    u16* hdst = hs + (size_t)(t + 1) * (NB * NH);
#pragma unroll
    for (int n = 0; n < 2; ++n) {
      float ig = sigm(acc[n][0]);
      float fg = sigm(acc[n][1]);
      float gg = tanh_f(acc[n][2]);
      float og = sigm(acc[n][3]);
      float cn = fg * creg[n] + ig * gg;
      creg[n] = cn;
      float hn = og * tanh_f(cn);
      dc_store_u16(&hdst[(b0 + n * 16) * NH + jm], f2bf(hn));
      if (t == NT - 1) {
        out_tail[(b0 + n * 16) * NH + jm] = hn;             // h_T
        out_tail[NB * NH + (b0 + n * 16) * NH + jm] = cn;   // c_T
      }
    }
    if (t < NT - 1) {
      // release: drain own h stores, then WG-wide rendezvous on L3 counter
      asm volatile("s_waitcnt vmcnt(0)" ::: "memory");
      __syncthreads();
      if (tid == 0) {
        __hip_atomic_fetch_add(bar, 1u, __ATOMIC_RELAXED, __HIP_MEMORY_SCOPE_AGENT);
        unsigned tgt = 128u * (unsigned)(t + 1);
        while (__hip_atomic_load(bar, __ATOMIC_RELAXED, __HIP_MEMORY_SCOPE_AGENT) < tgt) {}
      }
      __syncthreads();  // also protects LDS h-slice overwrite next step
    }
  }
}

// ---------------------------------------------------------------------------
// Kernel 4: logits = hs[1..T] @ W_out^T + b_out  -> fp32 into d_out rows (b*T+t)
// ---------------------------------------------------------------------------
__global__ __launch_bounds__(256) void logits_kernel(
    const u16* __restrict__ hs, const u16* __restrict__ wout_b,
    const float* __restrict__ b_out, float* __restrict__ out) {
  int mTile = blockIdx.y, nTile = blockIdx.x;
  int tid = threadIdx.x, w = tid >> 6, lane = tid & 63, l15 = lane & 15, l4 = lane >> 4;
  int mOff = (w & 1) * 64, nOff = (w >> 1) * 64;
  const u16* A = hs + (size_t)NB * NH;  // skip h0; row m = t*NB + b
  f32x4 acc[4][4] = {};
  for (int kk = 0; kk < 16; ++kk) {
    int k0 = kk * 32 + l4 * 8;
    bf16x8 a[4], bb[4];
    for (int fm = 0; fm < 4; ++fm) {
      int m = mTile * 128 + mOff + fm * 16 + l15;
      a[fm] = *(const bf16x8*)(A + (size_t)m * NH + k0);
    }
    for (int fn = 0; fn < 4; ++fn) {
      int v = nTile * 128 + nOff + fn * 16 + l15;
      bb[fn] = *(const bf16x8*)(wout_b + (size_t)v * NH + k0);
    }
    for (int fm = 0; fm < 4; ++fm)
      for (int fn = 0; fn < 4; ++fn)
        acc[fm][fn] = MFMA16(a[fm], bb[fn], acc[fm][fn]);
  }
  for (int fn = 0; fn < 4; ++fn) {
    int v = nTile * 128 + nOff + fn * 16 + l15;
    float bias = b_out[v];
    for (int fm = 0; fm < 4; ++fm)
      for (int i2 = 0; i2 < 4; ++i2) {
        int m = mTile * 128 + mOff + fm * 16 + l4 * 4 + i2;
        int b = m & (NB - 1), tt = m >> 7;
        out[((size_t)b * NT + tt) * NV + v] = acc[fm][fn][i2] + bias;
      }
  }
}

// ---------------------------------------------------------------------------
// Kernel 5: in-place row log_softmax over V=1024. One wave per row.
// ---------------------------------------------------------------------------
__global__ __launch_bounds__(256) void lsm_kernel(float* __restrict__ out) {
  int row = blockIdx.x * 4 + (threadIdx.x >> 6);
  int lane = threadIdx.x & 63;
  float* p = out + (size_t)row * NV + lane * 4;
  float4 x[4];
  float m = -1e30f;
#pragma unroll
  for (int i = 0; i < 4; ++i) {
    x[i] = *(const float4*)(p + i * 256);
    m = fmaxf(m, fmaxf(fmaxf(x[i].x, x[i].y), fmaxf(x[i].z, x[i].w)));
  }
#pragma unroll
  for (int o = 1; o < 64; o <<= 1) m = fmaxf(m, __shfl_xor(m, o, 64));
  float s = 0.f;
#pragma unroll
  for (int i = 0; i < 4; ++i)
    s += __expf(x[i].x - m) + __expf(x[i].y - m) + __expf(x[i].z - m) + __expf(x[i].w - m);
#pragma unroll
  for (int o = 1; o < 64; o <<= 1) s += __shfl_xor(s, o, 64);
  float lse = m + __logf(s);
#pragma unroll
  for (int i = 0; i < 4; ++i) {
    float4 y = x[i];
    y.x -= lse; y.y -= lse; y.z -= lse; y.w -= lse;
    *(float4*)(p + i * 256) = y;
  }
}

extern "C" void kernel_launch(void* const* d_in, const int* in_sizes, int n_in,
                              void* d_out, int out_size, void* d_ws, size_t ws_size,
                              hipStream_t stream) {
  (void)in_sizes; (void)n_in; (void)out_size; (void)ws_size;
  const float* enc_h  = (const float*)d_in[1];
  const float* enc_c  = (const float*)d_in[2];
  const int*   target = (const int*)d_in[3];
  const float* emb    = (const float*)d_in[4];
  const float* W_ih   = (const float*)d_in[5];
  const float* W_hh   = (const float*)d_in[6];
  const float* b_ih   = (const float*)d_in[7];
  const float* b_hh   = (const float*)d_in[8];
  const float* W_out  = (const float*)d_in[9];
  const float* b_out  = (const float*)d_in[10];

  char* ws = (char*)d_ws;
  u16*   wih_p  = (u16*)(ws);                 // 2048x256 bf16   (1 MB)
  u16*   whh_p  = (u16*)(ws + 1048576);       // 2048x512 bf16   (2 MB)
  u16*   wout_b = (u16*)(ws + 3145728);       // 1024x512 bf16   (1 MB)
  float* bias_p = (float*)(ws + 4194304);     // 2048 f32
  u16*   hs     = (u16*)(ws + 4202496);       // (T+1)x128x512 bf16 (64.1 MB)
  unsigned* bar = (unsigned*)(ws + 71442432); // barrier counter

  u16*   gates  = (u16*)d_out;                       // 268 MB bf16, aliases log_probs
  float* out    = (float*)d_out;
  float* out_tail = out + (size_t)NB * NT * NV;      // h_T then c_T

  prep_kernel<<<dim3(2048), 256, 0, stream>>>(enc_h, W_ih, W_hh, b_ih, b_hh, W_out,
                                              wih_p, whh_p, wout_b, bias_p, hs, bar);
  gates_kernel<<<dim3(16, 512), 256, 0, stream>>>(target, emb, wih_p, bias_p, gates);
  {
    const float* enc_c_a = enc_c;
    const u16* gates_a = gates;
    const u16* whh_a = whh_p;
    u16* hs_a = hs;
    float* tail_a = out_tail;
    unsigned* bar_a = bar;
    void* args[] = {&enc_c_a, &gates_a, &whh_a, &hs_a, &tail_a, &bar_a};
    hipLaunchCooperativeKernel((const void*)lstm_kernel, dim3(128), dim3(256),
                               args, 0, stream);
  }
  logits_kernel<<<dim3(8, 512), 256, 0, stream>>>(hs, wout_b, b_out, out);
  lsm_kernel<<<16384, 256, 0, stream>>>(out);
}

// Round 3
// 4498.418 us; speedup vs baseline: 4.0847x; 1.0908x over previous
//
#include <hip/hip_runtime.h>

typedef unsigned short u16;
typedef short bf16x8 __attribute__((ext_vector_type(8)));
typedef float f32x4 __attribute__((ext_vector_type(4)));

#define NB 128
#define NT 512
#define NV 1024
#define NE 256
#define NH 512
#define NG 2048

__device__ __forceinline__ u16 f2bf(float f) {
  union { float f; unsigned u; } v; v.f = f;
  unsigned r = v.u + 0x7FFFu + ((v.u >> 16) & 1u);
  return (u16)(r >> 16);
}
__device__ __forceinline__ float bf2f(u16 u) {
  union { unsigned u; float f; } v; v.u = ((unsigned)u) << 16;
  return v.f;
}
__device__ __forceinline__ float sigm(float x) { return 1.f / (1.f + __expf(-x)); }
__device__ __forceinline__ float tanh_f(float x) {
  x = fminf(fmaxf(x, -20.f), 20.f);
  float e = __expf(2.f * x);
  return (e - 1.f) / (e + 1.f);
}

#define MFMA16(a, b, c) __builtin_amdgcn_mfma_f32_16x16x32_bf16((a), (b), (c), 0, 0, 0)

// device-coherent (cross-XCD, via shared L3) helpers — no cache flushes
__device__ __forceinline__ unsigned long long dc_load_u64(const void* p) {
  return __hip_atomic_load((const unsigned long long*)p, __ATOMIC_RELAXED,
                           __HIP_MEMORY_SCOPE_AGENT);
}
__device__ __forceinline__ void dc_store_u16(u16* p, u16 v) {
  __hip_atomic_store(p, v, __ATOMIC_RELAXED, __HIP_MEMORY_SCOPE_AGENT);
}
// exact-count prefetch load (1 instruction, cached path)
__device__ __forceinline__ uint2 pf_load_u64(const void* p) {
  uint2 r;
  asm volatile("global_load_dwordx2 %0, %1, off" : "=v"(r) : "v"(p) : "memory");
  return r;
}

// ---------------------------------------------------------------------------
// Kernel 1: weight prep (gate rows permuted r' = j*4 + gate), h0 into hs slot
// 0, flags zeroed.
// ---------------------------------------------------------------------------
__global__ __launch_bounds__(256) void prep_kernel(
    const float* __restrict__ enc_h, const float* __restrict__ W_ih,
    const float* __restrict__ W_hh, const float* __restrict__ b_ih,
    const float* __restrict__ b_hh, const float* __restrict__ W_out,
    u16* __restrict__ wih_p, u16* __restrict__ whh_p, u16* __restrict__ wout_b,
    float* __restrict__ bias_p, u16* __restrict__ hs0,
    unsigned* __restrict__ flags) {
  int idx = blockIdx.x * 256 + threadIdx.x;
  int stride = gridDim.x * 256;
  if (idx < 128) flags[idx] = 0;
  const int N0 = NG * NE, N1 = NG * NH, N2 = NV * NH, N3 = NG, N4 = NB * NH;
  int total = N0 + N1 + N2 + N3 + N4;
  for (int i = idx; i < total; i += stride) {
    int j = i;
    if (j < N0) {
      int r = j >> 8, k = j & 255;
      int orig = (r & 3) * NH + (r >> 2);
      wih_p[j] = f2bf(W_ih[orig * NE + k]);
    } else if ((j -= N0) < N1) {
      int r = j >> 9, k = j & 511;
      int orig = (r & 3) * NH + (r >> 2);
      whh_p[j] = f2bf(W_hh[orig * NH + k]);
    } else if ((j -= N1) < N2) {
      wout_b[j] = f2bf(W_out[j]);
    } else if ((j -= N2) < N3) {
      int orig = (j & 3) * NH + (j >> 2);
      bias_p[j] = b_ih[orig] + b_hh[orig];
    } else {
      j -= N3;
      hs0[j] = f2bf(0.5f * (enc_h[j] + enc_h[N4 + j]));
    }
  }
}

// ---------------------------------------------------------------------------
// Kernel 2: gates_x = relu(emb[tok]) @ W_ih_p^T + bias_p   -> bf16 (t,b,g')
// ---------------------------------------------------------------------------
__global__ __launch_bounds__(256) void gates_kernel(
    const int* __restrict__ target, const float* __restrict__ emb,
    const u16* __restrict__ wih_p, const float* __restrict__ bias_p,
    u16* __restrict__ gates) {
  __shared__ __align__(16) u16 As[NB * NE];  // 64 KB, 16B-granule xor swizzle
  int t = blockIdx.y, nTile = blockIdx.x, tid = threadIdx.x;
  for (int i = tid; i < NB * 64; i += 256) {
    int row = i >> 6, c = i & 63;
    int tok = (t == 0) ? 0 : target[row * NT + t - 1];
    float4 f = *(const float4*)(emb + (size_t)tok * NE + c * 4);
    ushort4 pk = make_ushort4(f2bf(fmaxf(f.x, 0.f)), f2bf(fmaxf(f.y, 0.f)),
                              f2bf(fmaxf(f.z, 0.f)), f2bf(fmaxf(f.w, 0.f)));
    int g = c >> 1;
    int off = row * NE + ((((g ^ (row & 7)) << 3)) | ((c & 1) << 2));
    *(ushort4*)&As[off] = pk;
  }
  __syncthreads();
  int w = tid >> 6, lane = tid & 63, l15 = lane & 15, l4 = lane >> 4;
  int mOff = (w & 1) * 64, nOff = (w >> 1) * 64;
  f32x4 acc[4][4] = {};
  for (int kk = 0; kk < 8; ++kk) {
    bf16x8 a[4], bb[4];
    for (int fm = 0; fm < 4; ++fm) {
      int row = mOff + fm * 16 + l15;
      a[fm] = *(const bf16x8*)&As[row * NE + (((kk * 4 + l4) ^ (row & 7)) << 3)];
    }
    int k0 = kk * 32 + l4 * 8;
    for (int fn = 0; fn < 4; ++fn) {
      int n = nTile * 128 + nOff + fn * 16 + l15;
      bb[fn] = *(const bf16x8*)(wih_p + (size_t)n * NE + k0);
    }
    for (int fm = 0; fm < 4; ++fm)
      for (int fn = 0; fn < 4; ++fn)
        acc[fm][fn] = MFMA16(a[fm], bb[fn], acc[fm][fn]);
  }
  for (int fn = 0; fn < 4; ++fn) {
    int n = nTile * 128 + nOff + fn * 16 + l15;
    float bias = bias_p[n];
    for (int fm = 0; fm < 4; ++fm)
      for (int i2 = 0; i2 < 4; ++i2) {
        int row = mOff + fm * 16 + l4 * 4 + i2;
        gates[((size_t)t * NB + row) * NG + n] = f2bf(acc[fm][fn][i2] + bias);
      }
  }
}

// ---------------------------------------------------------------------------
// Kernel 3: persistent LSTM scan. Distributed-flag L3 barrier (one flag per
// WG, no same-address RMW serialization); all waves poll in parallel. gates
// for step t+1 prefetched via exact-count asm loads so only the 2 h-stores
// are drained (vmcnt(2)) before the flag store.
// ---------------------------------------------------------------------------
__global__ __launch_bounds__(256) void lstm_kernel(
    const float* __restrict__ enc_c, const u16* __restrict__ gates,
    const u16* __restrict__ whh_p, u16* __restrict__ hs,
    float* __restrict__ out_tail, unsigned* __restrict__ flags) {
  __shared__ __align__(16) u16 Hs[32 * NH];  // 32 KB h-slice, xor-swizzled
  int bid = blockIdx.x;
  int gb = bid & 3, gj = bid >> 2;
  int tid = threadIdx.x;
  int w = tid >> 6, lane = tid & 63, l15 = lane & 15, l4 = lane >> 4;
  int jm = gj * 16 + w * 4 + l4;  // this lane's j index
  int b0 = gb * 32 + l15;         // batch (n=0); n=1 -> +16

  // W_hh A-fragments into registers: row gj*64 + w*16 + l15, k = kk*32+l4*8
  bf16x8 wreg[16];
  {
    const u16* wp = whh_p + (size_t)(gj * 64 + w * 16 + l15) * NH + l4 * 8;
#pragma unroll
    for (int kk = 0; kk < 16; ++kk) wreg[kk] = *(const bf16x8*)(wp + kk * 32);
  }
  float creg[2];
  creg[0] = 0.5f * (enc_c[b0 * NH + jm] + enc_c[NB * NH + b0 * NH + jm]);
  creg[1] = 0.5f * (enc_c[(b0 + 16) * NH + jm] + enc_c[NB * NH + (b0 + 16) * NH + jm]);

  // prefetch gates for t=0
  uint2 pg0, pg1;
  {
    const u16* gp = gates + (size_t)b0 * NG + jm * 4;
    pg0 = pf_load_u64(gp);
    pg1 = pf_load_u64(gp + 16 * NG);
  }

  // initial stage of h[0] (written by prep, visible via kernel-boundary flush)
  {
    const u16* hsrc = hs + (size_t)gb * 32 * NH;
#pragma unroll
    for (int j = 0; j < 8; ++j) {
      int ch = j * 256 + tid;
      int row = ch >> 6, c = ch & 63;
      const u16* src = hsrc + row * NH + c * 8;
      unsigned long long q0 = dc_load_u64(src);
      unsigned long long q1 = dc_load_u64(src + 4);
      u16* dst = &Hs[row * NH + ((c ^ (row & 7)) << 3)];
      ((unsigned long long*)dst)[0] = q0;
      ((unsigned long long*)dst)[1] = q1;
    }
  }
  __syncthreads();

  const unsigned long long* f64 = (const unsigned long long*)flags;

  for (int t = 0; t < NT; ++t) {
    asm volatile("s_waitcnt vmcnt(0)" ::: "memory");  // pg0/pg1 ready
    f32x4 acc[2];
    acc[0][0] = bf2f((u16)(pg0.x & 0xFFFF)); acc[0][1] = bf2f((u16)(pg0.x >> 16));
    acc[0][2] = bf2f((u16)(pg0.y & 0xFFFF)); acc[0][3] = bf2f((u16)(pg0.y >> 16));
    acc[1][0] = bf2f((u16)(pg1.x & 0xFFFF)); acc[1][1] = bf2f((u16)(pg1.x >> 16));
    acc[1][2] = bf2f((u16)(pg1.y & 0xFFFF)); acc[1][3] = bf2f((u16)(pg1.y >> 16));
#pragma unroll
    for (int kk = 0; kk < 16; ++kk) {
      int K = kk * 4 + l4;
      bf16x8 h0v = *(const bf16x8*)&Hs[l15 * NH + ((K ^ (l15 & 7)) << 3)];
      bf16x8 h1v = *(const bf16x8*)&Hs[(l15 + 16) * NH + ((K ^ (l15 & 7)) << 3)];
      acc[0] = MFMA16(wreg[kk], h0v, acc[0]);
      acc[1] = MFMA16(wreg[kk], h1v, acc[1]);
    }
    u16* hdst = hs + (size_t)(t + 1) * (NB * NH);
    float hn2[2], cn2[2];
#pragma unroll
    for (int n = 0; n < 2; ++n) {
      float ig = sigm(acc[n][0]);
      float fg = sigm(acc[n][1]);
      float gg = tanh_f(acc[n][2]);
      float og = sigm(acc[n][3]);
      float cn = fg * creg[n] + ig * gg;
      creg[n] = cn;
      cn2[n] = cn;
      hn2[n] = og * tanh_f(cn);
      dc_store_u16(&hdst[(b0 + n * 16) * NH + jm], f2bf(hn2[n]));
    }
    if (t == NT - 1) {
      for (int n = 0; n < 2; ++n) {
        out_tail[(b0 + n * 16) * NH + jm] = hn2[n];           // h_T
        out_tail[NB * NH + (b0 + n * 16) * NH + jm] = cn2[n]; // c_T
      }
      break;
    }
    // pin: h-stores above, then issue next-step gate prefetch (2 asm loads),
    // then drain exactly the 2 stores (FIFO vmcnt) leaving prefetches flying.
    asm volatile("" ::: "memory");
    {
      const u16* gp = gates + ((size_t)(t + 1) * NB + b0) * NG + jm * 4;
      pg0 = pf_load_u64(gp);
      pg1 = pf_load_u64(gp + 16 * NG);
    }
    asm volatile("s_waitcnt vmcnt(2)" ::: "memory");
    __syncthreads();
    if (tid == 0)
      __hip_atomic_store(&flags[bid], (unsigned)(t + 1), __ATOMIC_RELAXED,
                         __HIP_MEMORY_SCOPE_AGENT);
    // parallel poll: lane l watches flags[2l], flags[2l+1]
    unsigned tgt = (unsigned)(t + 1);
    bool ok;
    do {
      unsigned long long v = __hip_atomic_load(&f64[lane], __ATOMIC_RELAXED,
                                               __HIP_MEMORY_SCOPE_AGENT);
      ok = ((unsigned)v >= tgt) && ((unsigned)(v >> 32) >= tgt);
    } while (!__all(ok));
    asm volatile("" ::: "memory");
    // stage h[t+1]
    {
      const u16* hsrc = hs + (size_t)(t + 1) * (NB * NH) + (size_t)gb * 32 * NH;
#pragma unroll
      for (int j = 0; j < 8; ++j) {
        int ch = j * 256 + tid;
        int row = ch >> 6, c = ch & 63;
        const u16* src = hsrc + row * NH + c * 8;
        unsigned long long q0 = dc_load_u64(src);
        unsigned long long q1 = dc_load_u64(src + 4);
        u16* dst = &Hs[row * NH + ((c ^ (row & 7)) << 3)];
        ((unsigned long long*)dst)[0] = q0;
        ((unsigned long long*)dst)[1] = q1;
      }
    }
    __syncthreads();
  }
}

// ---------------------------------------------------------------------------
// Kernel 4: logits = hs[1..T] @ W_out^T + b_out  -> fp32 into d_out rows (b*T+t)
// ---------------------------------------------------------------------------
__global__ __launch_bounds__(256) void logits_kernel(
    const u16* __restrict__ hs, const u16* __restrict__ wout_b,
    const float* __restrict__ b_out, float* __restrict__ out) {
  int mTile = blockIdx.y, nTile = blockIdx.x;
  int tid = threadIdx.x, w = tid >> 6, lane = tid & 63, l15 = lane & 15, l4 = lane >> 4;
  int mOff = (w & 1) * 64, nOff = (w >> 1) * 64;
  const u16* A = hs + (size_t)NB * NH;  // skip h0; row m = t*NB + b
  f32x4 acc[4][4] = {};
  for (int kk = 0; kk < 16; ++kk) {
    int k0 = kk * 32 + l4 * 8;
    bf16x8 a[4], bb[4];
    for (int fm = 0; fm < 4; ++fm) {
      int m = mTile * 128 + mOff + fm * 16 + l15;
      a[fm] = *(const bf16x8*)(A + (size_t)m * NH + k0);
    }
    for (int fn = 0; fn < 4; ++fn) {
      int v = nTile * 128 + nOff + fn * 16 + l15;
      bb[fn] = *(const bf16x8*)(wout_b + (size_t)v * NH + k0);
    }
    for (int fm = 0; fm < 4; ++fm)
      for (int fn = 0; fn < 4; ++fn)
        acc[fm][fn] = MFMA16(a[fm], bb[fn], acc[fm][fn]);
  }
  for (int fn = 0; fn < 4; ++fn) {
    int v = nTile * 128 + nOff + fn * 16 + l15;
    float bias = b_out[v];
    for (int fm = 0; fm < 4; ++fm)
      for (int i2 = 0; i2 < 4; ++i2) {
        int m = mTile * 128 + mOff + fm * 16 + l4 * 4 + i2;
        int b = m & (NB - 1), tt = m >> 7;
        out[((size_t)b * NT + tt) * NV + v] = acc[fm][fn][i2] + bias;
      }
  }
}

// ---------------------------------------------------------------------------
// Kernel 5: in-place row log_softmax over V=1024. One wave per row.
// ---------------------------------------------------------------------------
__global__ __launch_bounds__(256) void lsm_kernel(float* __restrict__ out) {
  int row = blockIdx.x * 4 + (threadIdx.x >> 6);
  int lane = threadIdx.x & 63;
  float* p = out + (size_t)row * NV + lane * 4;
  float4 x[4];
  float m = -1e30f;
#pragma unroll
  for (int i = 0; i < 4; ++i) {
    x[i] = *(const float4*)(p + i * 256);
    m = fmaxf(m, fmaxf(fmaxf(x[i].x, x[i].y), fmaxf(x[i].z, x[i].w)));
  }
#pragma unroll
  for (int o = 1; o < 64; o <<= 1) m = fmaxf(m, __shfl_xor(m, o, 64));
  float s = 0.f;
#pragma unroll
  for (int i = 0; i < 4; ++i)
    s += __expf(x[i].x - m) + __expf(x[i].y - m) + __expf(x[i].z - m) + __expf(x[i].w - m);
#pragma unroll
  for (int o = 1; o < 64; o <<= 1) s += __shfl_xor(s, o, 64);
  float lse = m + __logf(s);
#pragma unroll
  for (int i = 0; i < 4; ++i) {
    float4 y = x[i];
    y.x -= lse; y.y -= lse; y.z -= lse; y.w -= lse;
    *(float4*)(p + i * 256) = y;
  }
}

extern "C" void kernel_launch(void* const* d_in, const int* in_sizes, int n_in,
                              void* d_out, int out_size, void* d_ws, size_t ws_size,
                              hipStream_t stream) {
  (void)in_sizes; (void)n_in; (void)out_size; (void)ws_size;
  const float* enc_h  = (const float*)d_in[1];
  const float* enc_c  = (const float*)d_in[2];
  const int*   target = (const int*)d_in[3];
  const float* emb    = (const float*)d_in[4];
  const float* W_ih   = (const float*)d_in[5];
  const float* W_hh   = (const float*)d_in[6];
  const float* b_ih   = (const float*)d_in[7];
  const float* b_hh   = (const float*)d_in[8];
  const float* W_out  = (const float*)d_in[9];
  const float* b_out  = (const float*)d_in[10];

  char* ws = (char*)d_ws;
  u16*   wih_p  = (u16*)(ws);                 // 2048x256 bf16   (1 MB)
  u16*   whh_p  = (u16*)(ws + 1048576);       // 2048x512 bf16   (2 MB)
  u16*   wout_b = (u16*)(ws + 3145728);       // 1024x512 bf16   (1 MB)
  float* bias_p = (float*)(ws + 4194304);     // 2048 f32
  u16*   hs     = (u16*)(ws + 4202496);       // (T+1)x128x512 bf16 (64.1 MB)
  unsigned* flags = (unsigned*)(ws + 71442432); // 128 u32 step flags

  u16*   gates  = (u16*)d_out;                       // 268 MB bf16, aliases log_probs
  float* out    = (float*)d_out;
  float* out_tail = out + (size_t)NB * NT * NV;      // h_T then c_T

  prep_kernel<<<dim3(2048), 256, 0, stream>>>(enc_h, W_ih, W_hh, b_ih, b_hh, W_out,
                                              wih_p, whh_p, wout_b, bias_p, hs, flags);
  gates_kernel<<<dim3(16, 512), 256, 0, stream>>>(target, emb, wih_p, bias_p, gates);
  {
    const float* enc_c_a = enc_c;
    const u16* gates_a = gates;
    const u16* whh_a = whh_p;
    u16* hs_a = hs;
    float* tail_a = out_tail;
    unsigned* flags_a = flags;
    void* args[] = {&enc_c_a, &gates_a, &whh_a, &hs_a, &tail_a, &flags_a};
    hipLaunchCooperativeKernel((const void*)lstm_kernel, dim3(128), dim3(256),
                               args, 0, stream);
  }
  logits_kernel<<<dim3(8, 512), 256, 0, stream>>>(hs, wout_b, b_out, out);
  lsm_kernel<<<16384, 256, 0, stream>>>(out);
}

// Round 4
// 4054.504 us; speedup vs baseline: 4.5319x; 1.1095x over previous
//
#include <hip/hip_runtime.h>

typedef unsigned short u16;
typedef unsigned long long u64;
typedef short bf16x8 __attribute__((ext_vector_type(8)));
typedef float f32x4 __attribute__((ext_vector_type(4)));

#define NB 128
#define NT 512
#define NV 1024
#define NE 256
#define NH 512
#define NG 2048

#define POISON 0xFFFFFFFFFFFFFFFFULL

__device__ __forceinline__ u16 f2bf(float f) {
  union { float f; unsigned u; } v; v.f = f;
  unsigned r = v.u + 0x7FFFu + ((v.u >> 16) & 1u);
  return (u16)(r >> 16);
}
__device__ __forceinline__ float bf2f(u16 u) {
  union { unsigned u; float f; } v; v.u = ((unsigned)u) << 16;
  return v.f;
}
__device__ __forceinline__ float sigm(float x) { return 1.f / (1.f + __expf(-x)); }
__device__ __forceinline__ float tanh_f(float x) {
  x = fminf(fmaxf(x, -20.f), 20.f);
  float e = __expf(2.f * x);
  return (e - 1.f) / (e + 1.f);
}

#define MFMA16(a, b, c) __builtin_amdgcn_mfma_f32_16x16x32_bf16((a), (b), (c), 0, 0, 0)

// device-coherent (cross-XCD, via shared L3) helpers — no cache flushes
__device__ __forceinline__ u64 dc_load_u64(const void* p) {
  return __hip_atomic_load((const u64*)p, __ATOMIC_RELAXED, __HIP_MEMORY_SCOPE_AGENT);
}
__device__ __forceinline__ void dc_store_u64(void* p, u64 v) {
  __hip_atomic_store((u64*)p, v, __ATOMIC_RELAXED, __HIP_MEMORY_SCOPE_AGENT);
}
// exact-count prefetch load (1 instruction, cached path)
__device__ __forceinline__ uint2 pf_load_u64(const void* p) {
  uint2 r;
  asm volatile("global_load_dwordx2 %0, %1, off" : "=v"(r) : "v"(p) : "memory");
  return r;
}

// ---------------------------------------------------------------------------
// Kernel 1: weight prep (gate rows permuted r' = j*4 + gate), h0 into hs slot
// 0, hs slots 1..T poisoned with 0xFFFF (-NaN bf16: unproducible by the LSTM,
// so consumers can poll the data itself — no flags, no release drain).
// ---------------------------------------------------------------------------
__global__ __launch_bounds__(256) void prep_kernel(
    const float* __restrict__ enc_h, const float* __restrict__ W_ih,
    const float* __restrict__ W_hh, const float* __restrict__ b_ih,
    const float* __restrict__ b_hh, const float* __restrict__ W_out,
    u16* __restrict__ wih_p, u16* __restrict__ whh_p, u16* __restrict__ wout_b,
    float* __restrict__ bias_p, u16* __restrict__ hs) {
  int idx = blockIdx.x * 256 + threadIdx.x;
  int stride = gridDim.x * 256;
  const int N0 = NG * NE, N1 = NG * NH, N2 = NV * NH, N3 = NG, N4 = NB * NH;
  int total = N0 + N1 + N2 + N3 + N4;
  for (int i = idx; i < total; i += stride) {
    int j = i;
    if (j < N0) {
      int r = j >> 8, k = j & 255;
      int orig = (r & 3) * NH + (r >> 2);
      wih_p[j] = f2bf(W_ih[orig * NE + k]);
    } else if ((j -= N0) < N1) {
      int r = j >> 9, k = j & 511;
      int orig = (r & 3) * NH + (r >> 2);
      whh_p[j] = f2bf(W_hh[orig * NH + k]);
    } else if ((j -= N1) < N2) {
      wout_b[j] = f2bf(W_out[j]);
    } else if ((j -= N2) < N3) {
      int orig = (j & 3) * NH + (j >> 2);
      bias_p[j] = b_ih[orig] + b_hh[orig];
    } else {
      j -= N3;
      hs[j] = f2bf(0.5f * (enc_h[j] + enc_h[N4 + j]));
    }
  }
  // poison hs slots 1..NT (u64 granules)
  u64* hp = (u64*)(hs + NB * NH);
  const int NP = NT * NB * NH / 4;
  for (int i = idx; i < NP; i += stride) hp[i] = POISON;
}

// ---------------------------------------------------------------------------
// Kernel 2: gates_x = relu(emb[tok]) @ W_ih_p^T + bias_p   -> bf16 (t,b,g')
// ---------------------------------------------------------------------------
__global__ __launch_bounds__(256) void gates_kernel(
    const int* __restrict__ target, const float* __restrict__ emb,
    const u16* __restrict__ wih_p, const float* __restrict__ bias_p,
    u16* __restrict__ gates) {
  __shared__ __align__(16) u16 As[NB * NE];  // 64 KB, 16B-granule xor swizzle
  int t = blockIdx.y, nTile = blockIdx.x, tid = threadIdx.x;
  for (int i = tid; i < NB * 64; i += 256) {
    int row = i >> 6, c = i & 63;
    int tok = (t == 0) ? 0 : target[row * NT + t - 1];
    float4 f = *(const float4*)(emb + (size_t)tok * NE + c * 4);
    ushort4 pk = make_ushort4(f2bf(fmaxf(f.x, 0.f)), f2bf(fmaxf(f.y, 0.f)),
                              f2bf(fmaxf(f.z, 0.f)), f2bf(fmaxf(f.w, 0.f)));
    int g = c >> 1;
    int off = row * NE + ((((g ^ (row & 7)) << 3)) | ((c & 1) << 2));
    *(ushort4*)&As[off] = pk;
  }
  __syncthreads();
  int w = tid >> 6, lane = tid & 63, l15 = lane & 15, l4 = lane >> 4;
  int mOff = (w & 1) * 64, nOff = (w >> 1) * 64;
  f32x4 acc[4][4] = {};
  for (int kk = 0; kk < 8; ++kk) {
    bf16x8 a[4], bb[4];
    for (int fm = 0; fm < 4; ++fm) {
      int row = mOff + fm * 16 + l15;
      a[fm] = *(const bf16x8*)&As[row * NE + (((kk * 4 + l4) ^ (row & 7)) << 3)];
    }
    int k0 = kk * 32 + l4 * 8;
    for (int fn = 0; fn < 4; ++fn) {
      int n = nTile * 128 + nOff + fn * 16 + l15;
      bb[fn] = *(const bf16x8*)(wih_p + (size_t)n * NE + k0);
    }
    for (int fm = 0; fm < 4; ++fm)
      for (int fn = 0; fn < 4; ++fn)
        acc[fm][fn] = MFMA16(a[fm], bb[fn], acc[fm][fn]);
  }
  for (int fn = 0; fn < 4; ++fn) {
    int n = nTile * 128 + nOff + fn * 16 + l15;
    float bias = bias_p[n];
    for (int fm = 0; fm < 4; ++fm)
      for (int i2 = 0; i2 < 4; ++i2) {
        int row = mOff + fm * 16 + l4 * 4 + i2;
        gates[((size_t)t * NB + row) * NG + n] = f2bf(acc[fm][fn][i2] + bias);
      }
  }
}

// ---------------------------------------------------------------------------
// Kernel 3: persistent LSTM scan, flagless poison-poll exchange.
// Producers pack 4 h values into one 8B agent store (atomic visibility);
// consumers poll their 32KB slice directly until non-poison, then LDS-stage.
// No release drain, no flags, double-buffered LDS (one sync per step).
// ---------------------------------------------------------------------------
__global__ __launch_bounds__(256) void lstm_kernel(
    const float* __restrict__ enc_c, const u16* __restrict__ gates,
    const u16* __restrict__ whh_p, u16* __restrict__ hs,
    float* __restrict__ out_tail) {
  __shared__ __align__(16) u16 Hs[2][32 * NH];  // 2 x 32 KB, xor-swizzled
  int bid = blockIdx.x;
  int gb = bid & 3, gj = bid >> 2;
  int tid = threadIdx.x;
  int w = tid >> 6, lane = tid & 63, l15 = lane & 15, l4 = lane >> 4;
  int jm = gj * 16 + w * 4 + l4;  // this lane's j index
  int b0 = gb * 32 + l15;         // batch (n=0); n=1 -> +16

  // W_hh A-fragments into registers: row gj*64 + w*16 + l15, k = kk*32+l4*8
  bf16x8 wreg[16];
  {
    const u16* wp = whh_p + (size_t)(gj * 64 + w * 16 + l15) * NH + l4 * 8;
#pragma unroll
    for (int kk = 0; kk < 16; ++kk) wreg[kk] = *(const bf16x8*)(wp + kk * 32);
  }
  float creg[2];
  creg[0] = 0.5f * (enc_c[b0 * NH + jm] + enc_c[NB * NH + b0 * NH + jm]);
  creg[1] = 0.5f * (enc_c[(b0 + 16) * NH + jm] + enc_c[NB * NH + (b0 + 16) * NH + jm]);

  // prefetch gates for t=0
  uint2 pg0, pg1;
  {
    const u16* gp = gates + (size_t)b0 * NG + jm * 4;
    pg0 = pf_load_u64(gp);
    pg1 = pf_load_u64(gp + 16 * NG);
  }

  // initial stage of h[0] (written by prep; no poison there)
  {
    const u16* hsrc = hs + (size_t)gb * 32 * NH;
#pragma unroll
    for (int j = 0; j < 8; ++j) {
      int ch = j * 256 + tid;
      int row = ch >> 6, c = ch & 63;
      const u16* src = hsrc + row * NH + c * 8;
      u64 q0 = dc_load_u64(src);
      u64 q1 = dc_load_u64(src + 4);
      u16* dst = &Hs[0][row * NH + ((c ^ (row & 7)) << 3)];
      ((u64*)dst)[0] = q0;
      ((u64*)dst)[1] = q1;
    }
  }
  __syncthreads();
  int cur = 0;

  for (int t = 0; t < NT; ++t) {
    asm volatile("s_waitcnt vmcnt(0)" ::: "memory");  // pg0/pg1 ready
    __builtin_amdgcn_sched_barrier(0);
    f32x4 acc[2];
    acc[0][0] = bf2f((u16)(pg0.x & 0xFFFF)); acc[0][1] = bf2f((u16)(pg0.x >> 16));
    acc[0][2] = bf2f((u16)(pg0.y & 0xFFFF)); acc[0][3] = bf2f((u16)(pg0.y >> 16));
    acc[1][0] = bf2f((u16)(pg1.x & 0xFFFF)); acc[1][1] = bf2f((u16)(pg1.x >> 16));
    acc[1][2] = bf2f((u16)(pg1.y & 0xFFFF)); acc[1][3] = bf2f((u16)(pg1.y >> 16));
#pragma unroll
    for (int kk = 0; kk < 16; ++kk) {
      int K = kk * 4 + l4;
      bf16x8 h0v = *(const bf16x8*)&Hs[cur][l15 * NH + ((K ^ (l15 & 7)) << 3)];
      bf16x8 h1v = *(const bf16x8*)&Hs[cur][(l15 + 16) * NH + ((K ^ (l15 & 7)) << 3)];
      acc[0] = MFMA16(wreg[kk], h0v, acc[0]);
      acc[1] = MFMA16(wreg[kk], h1v, acc[1]);
    }
    u16* hdst = hs + (size_t)(t + 1) * (NB * NH);
    float hn2[2], cn2[2];
#pragma unroll
    for (int n = 0; n < 2; ++n) {
      float ig = sigm(acc[n][0]);
      float fg = sigm(acc[n][1]);
      float gg = tanh_f(acc[n][2]);
      float og = sigm(acc[n][3]);
      float cn = fg * creg[n] + ig * gg;
      creg[n] = cn;
      cn2[n] = cn;
      hn2[n] = og * tanh_f(cn);
      // pack 4 j-adjacent h values (lanes l4=0..3) into one 8B store
      unsigned v = (unsigned)f2bf(hn2[n]);
      unsigned v2 = (unsigned)__shfl_xor((int)v, 16, 64);
      v = v | (v2 << 16);                       // valid on l4 even
      unsigned hi = (unsigned)__shfl_xor((int)v, 32, 64);
      if (l4 == 0) {
        u64 q = (u64)v | ((u64)hi << 32);
        dc_store_u64(&hdst[(b0 + n * 16) * NH + jm], q);
      }
    }
    if (t == NT - 1) {
      for (int n = 0; n < 2; ++n) {
        out_tail[(b0 + n * 16) * NH + jm] = hn2[n];           // h_T
        out_tail[NB * NH + (b0 + n * 16) * NH + jm] = cn2[n]; // c_T
      }
      break;
    }
    // prefetch gates for t+1 (stay in flight under the poll)
    {
      const u16* gp = gates + ((size_t)(t + 1) * NB + b0) * NG + jm * 4;
      pg0 = pf_load_u64(gp);
      pg1 = pf_load_u64(gp + 16 * NG);
    }
    // poll+stage h[t+1] into the other LDS buffer: issue all 16 loads, then
    // re-poll only the chunks still poisoned.
    {
      const u16* hsrc = hs + (size_t)(t + 1) * (NB * NH) + (size_t)gb * 32 * NH;
      u64 q[16];
#pragma unroll
      for (int j = 0; j < 8; ++j) {
        int ch = j * 256 + tid;
        int row = ch >> 6, c = ch & 63;
        const u16* src = hsrc + row * NH + c * 8;
        q[2 * j] = dc_load_u64(src);
        q[2 * j + 1] = dc_load_u64(src + 4);
      }
#pragma unroll
      for (int j = 0; j < 8; ++j) {
        int ch = j * 256 + tid;
        int row = ch >> 6, c = ch & 63;
        const u16* src = hsrc + row * NH + c * 8;
        while (q[2 * j] == POISON) q[2 * j] = dc_load_u64(src);
        while (q[2 * j + 1] == POISON) q[2 * j + 1] = dc_load_u64(src + 4);
        u16* dst = &Hs[cur ^ 1][row * NH + ((c ^ (row & 7)) << 3)];
        ((u64*)dst)[0] = q[2 * j];
        ((u64*)dst)[1] = q[2 * j + 1];
      }
    }
    __syncthreads();  // staging complete + all waves done reading Hs[cur]
    cur ^= 1;
  }
}

// ---------------------------------------------------------------------------
// Kernel 4: logits = hs[1..T] @ W_out^T + b_out  -> fp32 into d_out rows (b*T+t)
// ---------------------------------------------------------------------------
__global__ __launch_bounds__(256) void logits_kernel(
    const u16* __restrict__ hs, const u16* __restrict__ wout_b,
    const float* __restrict__ b_out, float* __restrict__ out) {
  int mTile = blockIdx.y, nTile = blockIdx.x;
  int tid = threadIdx.x, w = tid >> 6, lane = tid & 63, l15 = lane & 15, l4 = lane >> 4;
  int mOff = (w & 1) * 64, nOff = (w >> 1) * 64;
  const u16* A = hs + (size_t)NB * NH;  // skip h0; row m = t*NB + b
  f32x4 acc[4][4] = {};
  for (int kk = 0; kk < 16; ++kk) {
    int k0 = kk * 32 + l4 * 8;
    bf16x8 a[4], bb[4];
    for (int fm = 0; fm < 4; ++fm) {
      int m = mTile * 128 + mOff + fm * 16 + l15;
      a[fm] = *(const bf16x8*)(A + (size_t)m * NH + k0);
    }
    for (int fn = 0; fn < 4; ++fn) {
      int v = nTile * 128 + nOff + fn * 16 + l15;
      bb[fn] = *(const bf16x8*)(wout_b + (size_t)v * NH + k0);
    }
    for (int fm = 0; fm < 4; ++fm)
      for (int fn = 0; fn < 4; ++fn)
        acc[fm][fn] = MFMA16(a[fm], bb[fn], acc[fm][fn]);
  }
  for (int fn = 0; fn < 4; ++fn) {
    int v = nTile * 128 + nOff + fn * 16 + l15;
    float bias = b_out[v];
    for (int fm = 0; fm < 4; ++fm)
      for (int i2 = 0; i2 < 4; ++i2) {
        int m = mTile * 128 + mOff + fm * 16 + l4 * 4 + i2;
        int b = m & (NB - 1), tt = m >> 7;
        out[((size_t)b * NT + tt) * NV + v] = acc[fm][fn][i2] + bias;
      }
  }
}

// ---------------------------------------------------------------------------
// Kernel 5: in-place row log_softmax over V=1024. One wave per row.
// ---------------------------------------------------------------------------
__global__ __launch_bounds__(256) void lsm_kernel(float* __restrict__ out) {
  int row = blockIdx.x * 4 + (threadIdx.x >> 6);
  int lane = threadIdx.x & 63;
  float* p = out + (size_t)row * NV + lane * 4;
  float4 x[4];
  float m = -1e30f;
#pragma unroll
  for (int i = 0; i < 4; ++i) {
    x[i] = *(const float4*)(p + i * 256);
    m = fmaxf(m, fmaxf(fmaxf(x[i].x, x[i].y), fmaxf(x[i].z, x[i].w)));
  }
#pragma unroll
  for (int o = 1; o < 64; o <<= 1) m = fmaxf(m, __shfl_xor(m, o, 64));
  float s = 0.f;
#pragma unroll
  for (int i = 0; i < 4; ++i)
    s += __expf(x[i].x - m) + __expf(x[i].y - m) + __expf(x[i].z - m) + __expf(x[i].w - m);
#pragma unroll
  for (int o = 1; o < 64; o <<= 1) s += __shfl_xor(s, o, 64);
  float lse = m + __logf(s);
#pragma unroll
  for (int i = 0; i < 4; ++i) {
    float4 y = x[i];
    y.x -= lse; y.y -= lse; y.z -= lse; y.w -= lse;
    *(float4*)(p + i * 256) = y;
  }
}

extern "C" void kernel_launch(void* const* d_in, const int* in_sizes, int n_in,
                              void* d_out, int out_size, void* d_ws, size_t ws_size,
                              hipStream_t stream) {
  (void)in_sizes; (void)n_in; (void)out_size; (void)ws_size;
  const float* enc_h  = (const float*)d_in[1];
  const float* enc_c  = (const float*)d_in[2];
  const int*   target = (const int*)d_in[3];
  const float* emb    = (const float*)d_in[4];
  const float* W_ih   = (const float*)d_in[5];
  const float* W_hh   = (const float*)d_in[6];
  const float* b_ih   = (const float*)d_in[7];
  const float* b_hh   = (const float*)d_in[8];
  const float* W_out  = (const float*)d_in[9];
  const float* b_out  = (const float*)d_in[10];

  char* ws = (char*)d_ws;
  u16*   wih_p  = (u16*)(ws);                 // 2048x256 bf16   (1 MB)
  u16*   whh_p  = (u16*)(ws + 1048576);       // 2048x512 bf16   (2 MB)
  u16*   wout_b = (u16*)(ws + 3145728);       // 1024x512 bf16   (1 MB)
  float* bias_p = (float*)(ws + 4194304);     // 2048 f32
  u16*   hs     = (u16*)(ws + 4202496);       // (T+1)x128x512 bf16 (64.1 MB)

  u16*   gates  = (u16*)d_out;                       // 268 MB bf16, aliases log_probs
  float* out    = (float*)d_out;
  float* out_tail = out + (size_t)NB * NT * NV;      // h_T then c_T

  prep_kernel<<<dim3(2048), 256, 0, stream>>>(enc_h, W_ih, W_hh, b_ih, b_hh, W_out,
                                              wih_p, whh_p, wout_b, bias_p, hs);
  gates_kernel<<<dim3(16, 512), 256, 0, stream>>>(target, emb, wih_p, bias_p, gates);
  {
    const float* enc_c_a = enc_c;
    const u16* gates_a = gates;
    const u16* whh_a = whh_p;
    u16* hs_a = hs;
    float* tail_a = out_tail;
    void* args[] = {&enc_c_a, &gates_a, &whh_a, &hs_a, &tail_a};
    hipLaunchCooperativeKernel((const void*)lstm_kernel, dim3(128), dim3(256),
                               args, 0, stream);
  }
  logits_kernel<<<dim3(8, 512), 256, 0, stream>>>(hs, wout_b, b_out, out);
  lsm_kernel<<<16384, 256, 0, stream>>>(out);
}